// Round 1
// baseline (2447.904 us; speedup 1.0000x reference)
//
#include <hip/hip_runtime.h>

#define BNn 65536   // B*N
#define Dd  128

// ---------------------------------------------------------------- embed: x0 = in[BN,8]@W[8,128]+b
__global__ __launch_bounds__(256) void k_embed(const float* __restrict__ in,
                                               const float* __restrict__ W,
                                               const float* __restrict__ b,
                                               float* __restrict__ x0) {
  __shared__ float Ws[8 * 128];
  __shared__ float bs[128];
  __shared__ float ins[16];
  int t = threadIdx.x;
  for (int i = t; i < 1024; i += 256) Ws[i] = W[i];
  if (t < 128) bs[t] = b[t];
  int row0 = blockIdx.x * 2;
  if (t < 16) ins[t] = in[row0 * 8 + t];
  __syncthreads();
  int r = t >> 7, c = t & 127;
  float acc = bs[c];
#pragma unroll
  for (int k = 0; k < 8; k++) acc += ins[r * 8 + k] * Ws[k * 128 + c];
  x0[(long)(row0 + r) * 128 + c] = acc;
}

// ---------------------------------------------------------------- dinv[n] = rsqrt(#valid+1)
__global__ void k_deg(const int* __restrict__ adj, float* __restrict__ dinv) {
  int n = blockIdx.x * 256 + threadIdx.x;
  int cnt = 0;
#pragma unroll
  for (int j = 0; j < 16; j++) cnt += (adj[(long)n * 16 + j] >= 0) ? 1 : 0;
  dinv[n] = rsqrtf((float)cnt + 1.0f);
}

__global__ void k_zero(float* __restrict__ p, int n) {
  int i = blockIdx.x * 256 + threadIdx.x;
  if (i < n) p[i] = 0.0f;
}

// ---------------------------------------------------------------- C[BN,128] = A[BN,128]@W[128,128] (+bias)
__global__ __launch_bounds__(256) void k_mm128(const float* __restrict__ A,
                                               const float* __restrict__ W,
                                               const float* __restrict__ bias,
                                               float* __restrict__ C) {
  __shared__ float As[64 * 128];
  int t = threadIdx.x;
  long base = (long)blockIdx.x * 64 * 128;
  const float4* A4 = (const float4*)(A + base);
  float4* As4 = (float4*)As;
#pragma unroll
  for (int i = 0; i < 8; i++) As4[t + 256 * i] = A4[t + 256 * i];
  __syncthreads();
  int ty = t >> 5, tx = t & 31;  // 8 rows x 4 cols per thread
  float acc[8][4];
  float4 bv = make_float4(0.f, 0.f, 0.f, 0.f);
  if (bias) bv = *(const float4*)(bias + tx * 4);
#pragma unroll
  for (int i = 0; i < 8; i++) { acc[i][0] = bv.x; acc[i][1] = bv.y; acc[i][2] = bv.z; acc[i][3] = bv.w; }
  for (int k = 0; k < 128; k++) {
    float4 w = *(const float4*)(W + k * 128 + tx * 4);
#pragma unroll
    for (int i = 0; i < 8; i++) {
      float a = As[(ty * 8 + i) * 128 + k];
      acc[i][0] += a * w.x; acc[i][1] += a * w.y; acc[i][2] += a * w.z; acc[i][3] += a * w.w;
    }
  }
#pragma unroll
  for (int i = 0; i < 8; i++) {
    float4 o = make_float4(acc[i][0], acc[i][1], acc[i][2], acc[i][3]);
    *(float4*)(C + base + (ty * 8 + i) * 128 + tx * 4) = o;
  }
}

// ---------------------------------------------------------------- GCN aggregate
__global__ __launch_bounds__(256) void k_gcn_agg(const float* __restrict__ hw,
                                                 const int* __restrict__ adj,
                                                 const float* __restrict__ dinv,
                                                 const float* __restrict__ gb,
                                                 float* __restrict__ out, int relu) {
  __shared__ float en[2][16];
  __shared__ int cols[2][16];
  int t = threadIdx.x;
  int row0 = blockIdx.x * 2;
  if (t < 32) {
    int lr = t >> 4, j = t & 15;
    int n = row0 + lr;
    int bb = n >> 10;
    int a = adj[(long)n * 16 + j];
    int valid = a >= 0;
    int cc = (valid ? a : 0) + (bb << 10);
    cols[lr][j] = cc;
    en[lr][j] = valid ? dinv[n] * dinv[cc] : 0.0f;
  }
  __syncthreads();
  int lr = t >> 7, c = t & 127;
  int n = row0 + lr;
  float di = dinv[n];
  float acc = hw[(long)n * 128 + c] * di * di + gb[c];
#pragma unroll
  for (int j = 0; j < 16; j++) acc += en[lr][j] * hw[(long)cols[lr][j] * 128 + c];
  out[(long)n * 128 + c] = relu ? fmaxf(acc, 0.0f) : acc;
}

// ---------------------------------------------------------------- rowwise LN (*g+b) + relu (in-place safe)
__global__ __launch_bounds__(128) void k_ln_relu(const float* __restrict__ X,
                                                 const float* __restrict__ g,
                                                 const float* __restrict__ b,
                                                 float* __restrict__ Y) {
  __shared__ float s1[128], s2[128];
  int t = threadIdx.x;
  long r = blockIdx.x;
  float v = X[r * 128 + t];
  s1[t] = v; s2[t] = v * v;
  __syncthreads();
  for (int o = 64; o > 0; o >>= 1) {
    if (t < o) { s1[t] += s1[t + o]; s2[t] += s2[t + o]; }
    __syncthreads();
  }
  float mean = s1[0] * (1.0f / 128.0f);
  float var = s2[0] * (1.0f / 128.0f) - mean * mean;
  float rs = rsqrtf(var + 1e-5f);
  float y = (v - mean) * rs * g[t] + b[t];
  Y[r * 128 + t] = fmaxf(y, 0.0f);
}

// ---------------------------------------------------------------- pass1: kvs partials, ksum, Sq, Sk
__global__ __launch_bounds__(256) void k_pass1(const float* __restrict__ z0,
                                               const float* __restrict__ Wq, const float* __restrict__ bq,
                                               const float* __restrict__ Wk, const float* __restrict__ bk,
                                               const float* __restrict__ Wv, const float* __restrict__ bv,
                                               float* __restrict__ part, float* __restrict__ ksum,
                                               float* __restrict__ Sq, float* __restrict__ Sk) {
  __shared__ float zs[32 * 128];
  __shared__ float kt[32 * 128];
  __shared__ float vt[32 * 128];
  __shared__ float red[256];
  int t = threadIdx.x;
  int h = blockIdx.y, chunk = blockIdx.x;
  int m = t & 127, l0 = t >> 7;
  int ty = t >> 4, tx = t & 15;
  float acc[8][8];
#pragma unroll
  for (int i = 0; i < 8; i++)
#pragma unroll
    for (int j = 0; j < 8; j++) acc[i][j] = 0.0f;
  float sq = 0.f, sk2 = 0.f, ksloc = 0.f;
  float bqv = bq[h * 128 + m], bkv = bk[h * 128 + m], bvv = bv[h * 128 + m];
  for (int s = 0; s < 32; s++) {
    __syncthreads();
    const float4* zg = (const float4*)(z0 + ((long)chunk * 1024 + s * 32) * 128);
    float4* zs4 = (float4*)zs;
#pragma unroll
    for (int i = 0; i < 4; i++) zs4[t + 256 * i] = zg[t + 256 * i];
    __syncthreads();
    float ak[16], av[16], aq[16];
#pragma unroll
    for (int i = 0; i < 16; i++) { ak[i] = 0.f; av[i] = 0.f; aq[i] = 0.f; }
    for (int kk = 0; kk < 128; kk++) {
      float wk = Wk[kk * 512 + h * 128 + m];
      float wv = Wv[kk * 512 + h * 128 + m];
      float wq = Wq[kk * 512 + h * 128 + m];
#pragma unroll
      for (int i = 0; i < 16; i++) {
        float z = zs[(l0 + 2 * i) * 128 + kk];
        ak[i] += z * wk; av[i] += z * wv; aq[i] += z * wq;
      }
    }
#pragma unroll
    for (int i = 0; i < 16; i++) {
      int l = l0 + 2 * i;
      float kvv = ak[i] + bkv, vvv = av[i] + bvv, qv = aq[i] + bqv;
      kt[l * 128 + m] = kvv; vt[l * 128 + m] = vvv;
      sk2 += kvv * kvv; sq += qv * qv;
    }
    __syncthreads();
    if (t < 128) {
      float s2 = 0.f;
      for (int l = 0; l < 32; l++) s2 += kt[l * 128 + t];
      ksloc += s2;
    }
    for (int l = 0; l < 32; l++) {
      float kv[8], vv[8];
#pragma unroll
      for (int i = 0; i < 8; i++) kv[i] = kt[l * 128 + ty * 8 + i];
#pragma unroll
      for (int j = 0; j < 8; j++) vv[j] = vt[l * 128 + tx * 8 + j];
#pragma unroll
      for (int i = 0; i < 8; i++)
#pragma unroll
        for (int j = 0; j < 8; j++) acc[i][j] += kv[i] * vv[j];
    }
  }
  float* P = part + ((long)(h * 64 + chunk)) * 16384;
#pragma unroll
  for (int i = 0; i < 8; i++)
#pragma unroll
    for (int j = 0; j < 8; j++) P[(ty * 8 + i) * 128 + tx * 8 + j] = acc[i][j];
  if (t < 128) atomicAdd(&ksum[h * 128 + t], ksloc);
  red[t] = sq; __syncthreads();
  for (int o = 128; o > 0; o >>= 1) { if (t < o) red[t] += red[t + o]; __syncthreads(); }
  if (t == 0) atomicAdd(Sq, red[0]);
  __syncthreads();
  red[t] = sk2; __syncthreads();
  for (int o = 128; o > 0; o >>= 1) { if (t < o) red[t] += red[t + o]; __syncthreads(); }
  if (t == 0) atomicAdd(Sk, red[0]);
}

// ---------------------------------------------------------------- reduce kvs partials
__global__ void k_reduce(const float* __restrict__ part, float* __restrict__ kvs) {
  int g = blockIdx.x * 256 + threadIdx.x;  // 0..65535
  int h = g >> 14, e = g & 16383;
  float s = 0.f;
  for (int c = 0; c < 64; c++) s += part[((long)(h * 64 + c)) * 16384 + e];
  kvs[g] = s;
}

// ---------------------------------------------------------------- pass2: attn -> z -> pre
__global__ __launch_bounds__(256) void k_pass2(const float* __restrict__ z0,
                                               const float* __restrict__ gnn,
                                               const float* __restrict__ Wq, const float* __restrict__ bq,
                                               const float* __restrict__ Wv, const float* __restrict__ bv,
                                               const float* __restrict__ kvs, const float* __restrict__ ksum,
                                               const float* __restrict__ SqSk,
                                               const float* __restrict__ g2, const float* __restrict__ b2v,
                                               float* __restrict__ pre) {
  __shared__ float zs[16 * 128];  // reused as y buffer later
  __shared__ float qt[16 * 512];
  __shared__ float vt[16 * 512];
  __shared__ float den[64];
  __shared__ float red1[256], red2[256];
  __shared__ float mu[16], rstd[16];
  int t = threadIdx.x;
  long n0 = (long)blockIdx.x * 16;
  const float4* z4 = (const float4*)(z0 + n0 * 128);
  float4* zs4 = (float4*)zs;
  zs4[t] = z4[t]; zs4[t + 256] = z4[t + 256];
  __syncthreads();
  float aq0[16], aq1[16], av0[16], av1[16];
#pragma unroll
  for (int l = 0; l < 16; l++) { aq0[l] = 0.f; aq1[l] = 0.f; av0[l] = 0.f; av1[l] = 0.f; }
  for (int kk = 0; kk < 128; kk++) {
    float wq0 = Wq[kk * 512 + t], wq1 = Wq[kk * 512 + t + 256];
    float wv0 = Wv[kk * 512 + t], wv1 = Wv[kk * 512 + t + 256];
#pragma unroll
    for (int l = 0; l < 16; l++) {
      float z = zs[l * 128 + kk];
      aq0[l] += z * wq0; aq1[l] += z * wq1; av0[l] += z * wv0; av1[l] += z * wv1;
    }
  }
  {
    float bq0 = bq[t], bq1 = bq[t + 256], bv0 = bv[t], bv1 = bv[t + 256];
#pragma unroll
    for (int l = 0; l < 16; l++) {
      qt[l * 512 + t] = aq0[l] + bq0; qt[l * 512 + t + 256] = aq1[l] + bq1;
      vt[l * 512 + t] = av0[l] + bv0; vt[l * 512 + t + 256] = av1[l] + bv1;
    }
  }
  __syncthreads();
  float inv = rsqrtf(SqSk[0] * SqSk[1]);  // 1/(||q||*||k||)
  if (t < 64) {
    int l = t >> 2, h = t & 3;
    float s = 0.f;
    for (int m = 0; m < 128; m++) s += qt[l * 512 + h * 128 + m] * ksum[h * 128 + m];
    den[t] = s * inv + 65536.0f;
  }
  __syncthreads();
  int d = t & 127, p = t >> 7;
  float attn[8];
#pragma unroll
  for (int i = 0; i < 8; i++) attn[i] = 0.f;
  for (int h = 0; h < 4; h++) {
    float hacc[8];
#pragma unroll
    for (int i = 0; i < 8; i++) hacc[i] = 0.f;
    const float* kc = kvs + h * 16384 + d;
    for (int m = 0; m < 128; m++) {
      float w = kc[m * 128];
#pragma unroll
      for (int i = 0; i < 8; i++) hacc[i] += qt[(p + 2 * i) * 512 + h * 128 + m] * w;
    }
#pragma unroll
    for (int i = 0; i < 8; i++) {
      int l = p + 2 * i;
      attn[i] += (hacc[i] * inv + 65536.0f * vt[l * 512 + h * 128 + d]) / den[l * 4 + h];
    }
  }
  // y = 0.5*mean_h(attn) + 0.5*z0  (mean over 4 heads -> 0.125 * sum)
#pragma unroll
  for (int i = 0; i < 8; i++) {
    int l = p + 2 * i;
    float y = 0.125f * attn[i] + 0.5f * z0[(n0 + l) * 128 + d];
    zs[l * 128 + d] = y;
  }
  __syncthreads();
  {
    int l = t >> 4, j = t & 15;
    float s1 = 0.f, s2 = 0.f;
    for (int q2 = 0; q2 < 8; q2++) { float v = zs[l * 128 + j * 8 + q2]; s1 += v; s2 += v * v; }
    red1[t] = s1; red2[t] = s2;
  }
  __syncthreads();
  if (t < 16) {
    float a = 0.f, c = 0.f;
    for (int j = 0; j < 16; j++) { a += red1[t * 16 + j]; c += red2[t * 16 + j]; }
    float m = a * (1.0f / 128.0f);
    mu[t] = m; rstd[t] = rsqrtf(c * (1.0f / 128.0f) - m * m + 1e-5f);
  }
  __syncthreads();
#pragma unroll
  for (int i = 0; i < 8; i++) {
    int l = p + 2 * i; long n = n0 + l;
    float y = zs[l * 128 + d];
    float zr = fmaxf((y - mu[l]) * rstd[l] * g2[d] + b2v[d], 0.0f);
    pre[n * 128 + d] = 0.8f * gnn[n * 128 + d] + 0.2f * zr;
  }
}

// ---------------------------------------------------------------- decoder (per batch element)
__global__ __launch_bounds__(256) void k_decoder(const float* __restrict__ enh, const int* __restrict__ cidx,
                                                 const float* __restrict__ kd, const float* __restrict__ vd,
                                                 const float* __restrict__ dWq, const float* __restrict__ dWo,
                                                 const float* __restrict__ ln1g, const float* __restrict__ ln1b,
                                                 const float* __restrict__ fW1, const float* __restrict__ fb1,
                                                 const float* __restrict__ fW2, const float* __restrict__ fb2,
                                                 const float* __restrict__ ln2g, const float* __restrict__ ln2b,
                                                 float* __restrict__ curO, float* __restrict__ globO) {
  __shared__ float cur[128], qd[128], att[128], tv[128], tn[128], f1[512];
  __shared__ float sc[4096];
  __shared__ float mu_s, rs_s;
  int b = blockIdx.x, t = threadIdx.x;
  int ci = cidx[b];
  const float* eb = enh + (long)b * 1024 * 128;
  if (t < 128) cur[t] = eb[(long)ci * 128 + t];
  __syncthreads();
  if (t < 128) {
    float s = 0.f;
    for (int k = 0; k < 128; k++) s += cur[k] * dWq[k * 128 + t];
    qd[t] = s;
  }
  __syncthreads();
  for (int i = 0; i < 16; i++) {
    int idx = t + 256 * i; int h = idx >> 10, n = idx & 1023;
    const float* kr = kd + ((long)b * 1024 + n) * 128 + h * 32;
    float s = 0.f;
#pragma unroll
    for (int e = 0; e < 32; e++) s += qd[h * 32 + e] * kr[e];
    sc[idx] = s * 0.17677669529663687f;  // 1/sqrt(32)
  }
  __syncthreads();
  {
    int h0 = t >> 6, j = t & 63;
    float mx = -1e30f;
    for (int k = 0; k < 16; k++) mx = fmaxf(mx, sc[h0 * 1024 + j + 64 * k]);
    for (int o = 32; o > 0; o >>= 1) mx = fmaxf(mx, __shfl_down(mx, o));
    mx = __shfl(mx, 0);
    float sm = 0.f;
    for (int k = 0; k < 16; k++) { float e2 = __expf(sc[h0 * 1024 + j + 64 * k] - mx); sc[h0 * 1024 + j + 64 * k] = e2; sm += e2; }
    for (int o = 32; o > 0; o >>= 1) sm += __shfl_down(sm, o);
    sm = __shfl(sm, 0);
    float invs = 1.0f / sm;
    for (int k = 0; k < 16; k++) sc[h0 * 1024 + j + 64 * k] *= invs;
  }
  __syncthreads();
  if (t < 128) {
    int h = t >> 5, e = t & 31;
    const float* vb = vd + (long)b * 1024 * 128 + h * 32 + e;
    float s = 0.f;
    for (int n = 0; n < 1024; n++) s += sc[h * 1024 + n] * vb[(long)n * 128];
    att[t] = s;
  }
  __syncthreads();
  if (t < 128) {
    float s = 0.f;
    for (int k = 0; k < 128; k++) s += att[k] * dWo[k * 128 + t];
    tv[t] = cur[t] + s;
  }
  __syncthreads();
  if (t == 0) {
    float s1 = 0.f, s2 = 0.f;
    for (int i = 0; i < 128; i++) { float v = tv[i]; s1 += v; s2 += v * v; }
    float m = s1 / 128.0f;
    mu_s = m; rs_s = rsqrtf(s2 / 128.0f - m * m + 1e-5f);
  }
  __syncthreads();
  if (t < 128) tn[t] = (tv[t] - mu_s) * rs_s * ln1g[t] + ln1b[t];
  __syncthreads();
  for (int i = 0; i < 2; i++) {
    int c = t + 256 * i;
    float s = fb1[c];
    for (int k = 0; k < 128; k++) s += tn[k] * fW1[k * 512 + c];
    f1[c] = fmaxf(s, 0.0f);
  }
  __syncthreads();
  if (t < 128) {
    float s = fb2[t];
    for (int k = 0; k < 512; k++) s += f1[k] * fW2[k * 128 + t];
    tv[t] = tn[t] + s;
  }
  __syncthreads();
  if (t == 0) {
    float s1 = 0.f, s2 = 0.f;
    for (int i = 0; i < 128; i++) { float v = tv[i]; s1 += v; s2 += v * v; }
    float m = s1 / 128.0f;
    mu_s = m; rs_s = rsqrtf(s2 / 128.0f - m * m + 1e-5f);
  }
  __syncthreads();
  if (t < 128) {
    globO[b * 128 + t] = (tv[t] - mu_s) * rs_s * ln2g[t] + ln2b[t];
    curO[b * 128 + t] = cur[t];
  }
}

// ---------------------------------------------------------------- Q head
__global__ __launch_bounds__(128) void k_qhead(const float* __restrict__ enh, const int* __restrict__ vps,
                                               const float* __restrict__ curb, const float* __restrict__ globb,
                                               const float* __restrict__ qW, const float* __restrict__ qb,
                                               float* __restrict__ out) {
  __shared__ float red[128];
  __shared__ float base_s;
  int b = blockIdx.x, t = threadIdx.x;
  red[t] = globb[b * 128 + t] * qW[t] + curb[b * 128 + t] * qW[128 + t];
  __syncthreads();
  for (int o = 64; o > 0; o >>= 1) { if (t < o) red[t] += red[t + o]; __syncthreads(); }
  if (t == 0) base_s = red[0] + qb[0];
  __syncthreads();
  int vi = vps[b * 128 + t];
  const float* er = enh + ((long)b * 1024 + vi) * 128;
  float s = 0.f;
  for (int i = 0; i < 128; i++) s += er[i] * qW[256 + i];
  out[b * 128 + t] = base_s + s;
}

// ================================================================ launch
extern "C" void kernel_launch(void* const* d_in, const int* in_sizes, int n_in,
                              void* d_out, int out_size, void* d_ws, size_t ws_size,
                              hipStream_t stream) {
  const float* node_in = (const float*)d_in[0];
  const int* cur_idx   = (const int*)d_in[2];
  const int* vps       = (const int*)d_in[3];
  const int* adj       = (const int*)d_in[5];
  const float* W_init  = (const float*)d_in[6];
  const float* b_init  = (const float*)d_in[7];
  const float* gcn_W   = (const float*)d_in[8];
  const float* gcn_b   = (const float*)d_in[9];
  const float* tc_fc_W = (const float*)d_in[10];
  const float* tc_fc_b = (const float*)d_in[11];
  const float* ln1g    = (const float*)d_in[12];
  const float* ln1b    = (const float*)d_in[13];
  const float* Wq      = (const float*)d_in[14];
  const float* bq      = (const float*)d_in[15];
  const float* Wk      = (const float*)d_in[16];
  const float* bk      = (const float*)d_in[17];
  const float* Wv      = (const float*)d_in[18];
  const float* bv      = (const float*)d_in[19];
  const float* ln2g    = (const float*)d_in[20];
  const float* ln2b    = (const float*)d_in[21];
  const float* sg_W    = (const float*)d_in[22];
  const float* sg_b    = (const float*)d_in[23];
  const float* dWq     = (const float*)d_in[24];
  const float* dWk     = (const float*)d_in[25];
  const float* dWv     = (const float*)d_in[26];
  const float* dWo     = (const float*)d_in[27];
  const float* dln1g   = (const float*)d_in[28];
  const float* dln1b   = (const float*)d_in[29];
  const float* fW1     = (const float*)d_in[30];
  const float* fb1     = (const float*)d_in[31];
  const float* fW2     = (const float*)d_in[32];
  const float* fb2     = (const float*)d_in[33];
  const float* dln2g   = (const float*)d_in[34];
  const float* dln2b   = (const float*)d_in[35];
  const float* qW      = (const float*)d_in[36];
  const float* qb      = (const float*)d_in[37];

  float* w = (float*)d_ws;
  const long BIG = (long)BNn * 128;           // 8.39M floats
  float* buf0 = w;                            // x0 -> kvs_part -> pre -> vd
  float* buf1 = w + BIG;                      // hw -> z0 -> enhanced
  float* buf2 = w + 2 * BIG;                  // gcn h/out -> kd
  float* dinv = w + 3 * BIG;                  // BN
  float* kvs  = dinv + BNn;                   // 65536
  float* ksum = kvs + 65536;                  // 512
  float* SqSk = ksum + 512;                   // 2
  float* curb = SqSk + 2;                     // 8192
  float* globb = curb + 8192;                 // 8192

  // embedding + degrees + zero accumulators
  k_embed<<<BNn / 2, 256, 0, stream>>>(node_in, W_init, b_init, buf0);
  k_deg<<<BNn / 256, 256, 0, stream>>>(adj, dinv);
  k_zero<<<3, 256, 0, stream>>>(ksum, 514);

  // GCN x4
  const float* h = buf0;
  for (int i = 0; i < 4; i++) {
    k_mm128<<<BNn / 64, 256, 0, stream>>>(h, gcn_W + (long)i * 16384, nullptr, buf1);
    k_gcn_agg<<<BNn / 2, 256, 0, stream>>>(buf1, adj, dinv, gcn_b + i * 128, buf2, (i < 3) ? 1 : 0);
    h = buf2;
  }
  // gnn_out = buf2

  // z0 = relu(LN(x0 @ tc_fc + b))
  k_mm128<<<BNn / 64, 256, 0, stream>>>(buf0, tc_fc_W, tc_fc_b, buf1);
  k_ln_relu<<<BNn, 128, 0, stream>>>(buf1, ln1g, ln1b, buf1);  // z0 = buf1

  // attention pass 1 (kvs partials into buf0, x0 dead)
  k_pass1<<<dim3(64, 4), 256, 0, stream>>>(buf1, Wq, bq, Wk, bk, Wv, bv, buf0, ksum, SqSk, SqSk + 1);
  k_reduce<<<256, 256, 0, stream>>>(buf0, kvs);

  // pass 2: attn -> z -> pre (into buf0)
  k_pass2<<<BNn / 16, 256, 0, stream>>>(buf1, buf2, Wq, bq, Wv, bv, kvs, ksum, SqSk, ln2g, ln2b, buf0);

  // enhanced = pre @ sg_fc (into buf1; z0 dead)
  k_mm128<<<BNn / 64, 256, 0, stream>>>(buf0, sg_W, sg_b, buf1);

  // decoder projections: kd=buf2 (gnn dead), vd=buf0 (pre dead)
  k_mm128<<<BNn / 64, 256, 0, stream>>>(buf1, dWk, nullptr, buf2);
  k_mm128<<<BNn / 64, 256, 0, stream>>>(buf1, dWv, nullptr, buf0);

  k_decoder<<<64, 256, 0, stream>>>(buf1, cur_idx, buf2, buf0, dWq, dWo, dln1g, dln1b,
                                    fW1, fb1, fW2, fb2, dln2g, dln2b, curb, globb);
  k_qhead<<<64, 128, 0, stream>>>(buf1, vps, curb, globb, qW, qb, (float*)d_out);
}

// Round 4
// 984.393 us; speedup vs baseline: 2.4867x; 2.4867x over previous
//
#include <hip/hip_runtime.h>

#define BNn 65536L   // B*N

typedef unsigned short u16;
typedef unsigned int u32;
typedef __attribute__((ext_vector_type(8))) short short8;
typedef __attribute__((ext_vector_type(4))) float f32x4;

__device__ inline u16 f2b(float f){ u32 u = __float_as_uint(f); u32 r = (u + 0x7fffu + ((u>>16)&1u))>>16; return (u16)r; }
__device__ inline float b2f(u16 b){ return __uint_as_float(((u32)b)<<16); }

// ---------------------------------------------------------------- weight prep: fp32 [K][N] -> bf16 [N][K]
__global__ void k_prep(const float* __restrict__ gcnW, const float* __restrict__ tcW,
                       const float* __restrict__ sgW, const float* __restrict__ dKW,
                       const float* __restrict__ dVW,
                       const float* __restrict__ Wq, const float* __restrict__ Wk, const float* __restrict__ Wv,
                       const float* __restrict__ bq, const float* __restrict__ bk, const float* __restrict__ bv,
                       u16* __restrict__ wts, float* __restrict__ bqkv) {
  int idx = blockIdx.x * 256 + threadIdx.x;
  if (idx < 1536) bqkv[idx] = idx < 512 ? bq[idx] : idx < 1024 ? bk[idx - 512] : bv[idx - 1024];
  if (idx >= 327680) return;
  if (idx < 131072) {
    int mtx = idx >> 14;            // 0..3 gcn, 4 tc, 5 sg, 6 dk, 7 dv
    int loc = idx & 16383; int n = loc >> 7, k = loc & 127;
    const float* src = mtx < 4 ? gcnW + mtx * 16384 : mtx == 4 ? tcW : mtx == 5 ? sgW : mtx == 6 ? dKW : dVW;
    wts[idx] = f2b(src[k * 128 + n]);
  } else {
    int loc = idx - 131072; int n = loc >> 7, k = loc & 127;   // n in [0,1536)
    int sec = n >> 9, col = n & 511;
    const float* src = sec == 0 ? Wq : sec == 1 ? Wk : Wv;
    wts[idx] = f2b(src[k * 512 + col]);
  }
}

// ---------------------------------------------------------------- embed
__global__ __launch_bounds__(256) void k_embed(const float* __restrict__ in,
                                               const float* __restrict__ W,
                                               const float* __restrict__ b,
                                               u16* __restrict__ x0) {
  __shared__ float Ws[8 * 128];
  __shared__ float bs[128];
  __shared__ float ins[16];
  int t = threadIdx.x;
  for (int i = t; i < 1024; i += 256) Ws[i] = W[i];
  if (t < 128) bs[t] = b[t];
  int row0 = blockIdx.x * 2;
  if (t < 16) ins[t] = in[row0 * 8 + t];
  __syncthreads();
  int r = t >> 7, c = t & 127;
  float acc = bs[c];
#pragma unroll
  for (int k = 0; k < 8; k++) acc += ins[r * 8 + k] * Ws[k * 128 + c];
  x0[(long)(row0 + r) * 128 + c] = f2b(acc);
}

__global__ void k_deg(const int* __restrict__ adj, float* __restrict__ dinv) {
  int n = blockIdx.x * 256 + threadIdx.x;
  int cnt = 0;
#pragma unroll
  for (int j = 0; j < 16; j++) cnt += (adj[(long)n * 16 + j] >= 0) ? 1 : 0;
  dinv[n] = rsqrtf((float)cnt + 1.0f);
}

__global__ void k_zero(float* __restrict__ p, int n) {
  int i = blockIdx.x * 256 + threadIdx.x;
  if (i < n) p[i] = 0.0f;
}

// ---------------------------------------------------------------- MFMA GEMM 64-row tile: C = A[BN,128]@WT^T (+bias)
// WT [128][128] bf16 (row = out col n, 128 k each). EPI: 0 bias, 1 bias+relu, 2 bias+LN+relu. In-place (C==A) safe.
template<int EPI>
__global__ __launch_bounds__(256) void k_gemm(const u16* __restrict__ A,
                                              const u16* __restrict__ WT,
                                              const float* __restrict__ bias,
                                              const float* __restrict__ lng,
                                              const float* __restrict__ lnb,
                                              u16* __restrict__ C) {
  __shared__ u16 sA[64 * 136];
  __shared__ u16 sW[128 * 136];
  int t = threadIdx.x;
  long row0 = (long)blockIdx.x * 64;
#pragma unroll
  for (int i = 0; i < 4; i++) {
    int idx = t + i * 256; int row = idx >> 4, ch = idx & 15;
    *(float4*)(sA + row * 136 + ch * 8) = *(const float4*)(A + (row0 + row) * 128 + ch * 8);
  }
#pragma unroll
  for (int i = 0; i < 8; i++) {
    int idx = t + i * 256; int row = idx >> 4, ch = idx & 15;
    *(float4*)(sW + row * 136 + ch * 8) = *(const float4*)(WT + row * 128 + ch * 8);
  }
  __syncthreads();
  int wave = t >> 6, lane = t & 63, m = lane & 15, g = lane >> 4;
  f32x4 acc[8];
#pragma unroll
  for (int c = 0; c < 8; c++) acc[c] = (f32x4){0.f, 0.f, 0.f, 0.f};
  const u16* aB = sA + (wave * 16 + m) * 136 + g * 8;
#pragma unroll
  for (int s = 0; s < 4; s++) {
    short8 a = *(const short8*)(aB + s * 32);
#pragma unroll
    for (int c = 0; c < 8; c++) {
      short8 bb = *(const short8*)(sW + (c * 16 + m) * 136 + g * 8 + s * 32);
      acc[c] = __builtin_amdgcn_mfma_f32_16x16x32_bf16(a, bb, acc[c], 0, 0, 0);
    }
  }
#pragma unroll
  for (int c = 0; c < 8; c++) {
    float bc = bias ? bias[c * 16 + m] : 0.0f;
#pragma unroll
    for (int r = 0; r < 4; r++) acc[c][r] += bc;
  }
  if (EPI == 2) {
    float gg[8], bb2[8];
#pragma unroll
    for (int c = 0; c < 8; c++) { gg[c] = lng[c * 16 + m]; bb2[c] = lnb[c * 16 + m]; }
#pragma unroll
    for (int r = 0; r < 4; r++) {
      float s1 = 0.f, s2 = 0.f;
#pragma unroll
      for (int c = 0; c < 8; c++) { float y = acc[c][r]; s1 += y; s2 += y * y; }
#pragma unroll
      for (int mask = 1; mask < 16; mask <<= 1) { s1 += __shfl_xor(s1, mask); s2 += __shfl_xor(s2, mask); }
      float mu = s1 * (1.f / 128.f);
      float rstd = rsqrtf(s2 * (1.f / 128.f) - mu * mu + 1e-5f);
#pragma unroll
      for (int c = 0; c < 8; c++)
        acc[c][r] = fmaxf((acc[c][r] - mu) * rstd * gg[c] + bb2[c], 0.f);
    }
  }
#pragma unroll
  for (int c = 0; c < 8; c++) {
    int col = c * 16 + m;
#pragma unroll
    for (int r = 0; r < 4; r++) {
      float y = acc[c][r];
      if (EPI == 1) y = fmaxf(y, 0.f);
      C[(row0 + wave * 16 + g * 4 + r) * 128 + col] = f2b(y);
    }
  }
}

// ---------------------------------------------------------------- GCN aggregate
__global__ __launch_bounds__(256) void k_agg(const u16* __restrict__ hw, const int* __restrict__ adj,
                                             const float* __restrict__ dinv, const float* __restrict__ gb,
                                             u16* __restrict__ out, int relu) {
  __shared__ float en[2][16];
  __shared__ int cols[2][16];
  int t = threadIdx.x;
  int row0 = blockIdx.x * 2;
  if (t < 32) {
    int lr = t >> 4, j = t & 15;
    int n = row0 + lr;
    int bb = n >> 10;
    int a = adj[(long)n * 16 + j];
    int valid = a >= 0;
    int cc = (valid ? a : 0) + (bb << 10);
    cols[lr][j] = cc;
    en[lr][j] = valid ? dinv[n] * dinv[cc] : 0.0f;
  }
  __syncthreads();
  int lr = t >> 7, c = t & 127;
  int n = row0 + lr;
  float di = dinv[n];
  float acc = b2f(hw[(long)n * 128 + c]) * di * di + gb[c];
#pragma unroll
  for (int j = 0; j < 16; j++) acc += en[lr][j] * b2f(hw[(long)cols[lr][j] * 128 + c]);
  out[(long)n * 128 + c] = f2b(relu ? fmaxf(acc, 0.0f) : acc);
}

// ---------------------------------------------------------------- fused q/k/v + kT*v partials + ksum/Sq/Sk
// grid (128 chunks, 4 heads); each block: 512 rows in 8 sub-tiles of 64
__global__ __launch_bounds__(256) void k_kvq(const u16* __restrict__ z0,
                                             const u16* __restrict__ wts,
                                             const float* __restrict__ bqkv,
                                             float* __restrict__ part,
                                             float* __restrict__ ksum,
                                             float* __restrict__ Sq, float* __restrict__ Sk) {
  __shared__ u16 sZ[64 * 136];
  __shared__ u16 sKT[128 * 72];
  __shared__ u16 sVT[128 * 72];
  __shared__ float ksred[128];
  __shared__ float red[8];
  int t = threadIdx.x;
  int chunk = blockIdx.x, h = blockIdx.y;
  int wave = t >> 6, lane = t & 63, m = lane & 15, g = lane >> 4;
  const u16* wq = wts + 131072 + (long)h * 16384;
  const u16* wk = wts + 196608 + (long)h * 16384;
  const u16* wv = wts + 262144 + (long)h * 16384;
  float bqv[8], bkv[8], bvv[8];
#pragma unroll
  for (int c = 0; c < 8; c++) {
    bqv[c] = bqkv[h * 128 + c * 16 + m];
    bkv[c] = bqkv[512 + h * 128 + c * 16 + m];
    bvv[c] = bqkv[1024 + h * 128 + c * 16 + m];
  }
  if (t < 128) ksred[t] = 0.f;
  f32x4 acc2[2][8];
#pragma unroll
  for (int i = 0; i < 2; i++)
#pragma unroll
    for (int c = 0; c < 8; c++) acc2[i][c] = (f32x4){0.f, 0.f, 0.f, 0.f};
  float ksloc[8] = {0.f, 0.f, 0.f, 0.f, 0.f, 0.f, 0.f, 0.f};
  float sq = 0.f, sk = 0.f;
  for (int s8 = 0; s8 < 8; s8++) {
    long r0 = (long)chunk * 512 + s8 * 64;
#pragma unroll
    for (int i = 0; i < 4; i++) {
      int idx = t + i * 256; int row = idx >> 4, ch = idx & 15;
      *(float4*)(sZ + row * 136 + ch * 8) = *(const float4*)(z0 + (r0 + row) * 128 + ch * 8);
    }
    __syncthreads();
    const u16* aB = sZ + (wave * 16 + m) * 136 + g * 8;
    short8 a[4];
#pragma unroll
    for (int s = 0; s < 4; s++) a[s] = *(const short8*)(aB + s * 32);
    f32x4 accq[8], acck[8], accv[8];
#pragma unroll
    for (int c = 0; c < 8; c++) { accq[c] = (f32x4){0.f,0.f,0.f,0.f}; acck[c] = accq[c]; accv[c] = accq[c]; }
#pragma unroll
    for (int s = 0; s < 4; s++) {
#pragma unroll
      for (int c = 0; c < 8; c++) {
        long wo = (long)(c * 16 + m) * 128 + g * 8 + s * 32;
        short8 bqf = *(const short8*)(wq + wo);
        short8 bkf = *(const short8*)(wk + wo);
        short8 bvf = *(const short8*)(wv + wo);
        accq[c] = __builtin_amdgcn_mfma_f32_16x16x32_bf16(a[s], bqf, accq[c], 0, 0, 0);
        acck[c] = __builtin_amdgcn_mfma_f32_16x16x32_bf16(a[s], bkf, acck[c], 0, 0, 0);
        accv[c] = __builtin_amdgcn_mfma_f32_16x16x32_bf16(a[s], bvf, accv[c], 0, 0, 0);
      }
    }
    __syncthreads();   // protect sKT/sVT against previous iteration's readers
#pragma unroll
    for (int c = 0; c < 8; c++) {
      float kk4 = 0.f;
      u16 kb[4], vb[4];
#pragma unroll
      for (int r = 0; r < 4; r++) {
        float qv = accq[c][r] + bqv[c]; sq += qv * qv;
        float kv = acck[c][r] + bkv[c]; sk += kv * kv; kk4 += kv; kb[r] = f2b(kv);
        float vv = accv[c][r] + bvv[c]; vb[r] = f2b(vv);
      }
      ksloc[c] += kk4;
      uint2 kp, vp;
      kp.x = ((u32)kb[1] << 16) | kb[0]; kp.y = ((u32)kb[3] << 16) | kb[2];
      vp.x = ((u32)vb[1] << 16) | vb[0]; vp.y = ((u32)vb[3] << 16) | vb[2];
      *(uint2*)(sKT + (c * 16 + m) * 72 + wave * 16 + g * 4) = kp;
      *(uint2*)(sVT + (c * 16 + m) * 72 + wave * 16 + g * 4) = vp;
    }
    __syncthreads();
#pragma unroll
    for (int i = 0; i < 2; i++) {
      const u16* aK = sKT + (wave * 32 + i * 16 + m) * 72 + g * 8;
#pragma unroll
      for (int s = 0; s < 2; s++) {
        short8 ak = *(const short8*)(aK + s * 32);
#pragma unroll
        for (int c = 0; c < 8; c++) {
          short8 bv8 = *(const short8*)(sVT + (c * 16 + m) * 72 + g * 8 + s * 32);
          acc2[i][c] = __builtin_amdgcn_mfma_f32_16x16x32_bf16(ak, bv8, acc2[i][c], 0, 0, 0);
        }
      }
    }
  }
  // reductions
#pragma unroll
  for (int c = 0; c < 8; c++) {
    float v = ksloc[c];
    v += __shfl_xor(v, 16); v += __shfl_xor(v, 32);
    if (g == 0) atomicAdd(&ksred[c * 16 + m], v);
  }
#pragma unroll
  for (int o = 1; o < 64; o <<= 1) { sq += __shfl_xor(sq, o); sk += __shfl_xor(sk, o); }
  if (lane == 0) { red[wave] = sq; red[4 + wave] = sk; }
  __syncthreads();
  if (t < 128) atomicAdd(&ksum[h * 128 + t], ksred[t]);
  if (t == 0) { atomicAdd(Sq, red[0] + red[1] + red[2] + red[3]); atomicAdd(Sk, red[4] + red[5] + red[6] + red[7]); }
  float* P = part + ((long)h * 128 + chunk) * 16384;
#pragma unroll
  for (int i = 0; i < 2; i++)
#pragma unroll
    for (int c = 0; c < 8; c++)
      *(f32x4*)(P + (long)(c * 16 + m) * 128 + wave * 32 + i * 16 + g * 4) = acc2[i][c];
}

// ---------------------------------------------------------------- reduce partials -> kvsT bf16 [h][dd][mm]
__global__ void k_kvs_reduce(const float* __restrict__ part, u16* __restrict__ kvsT) {
  int gidx = blockIdx.x * 256 + threadIdx.x;   // 65536
  int h = gidx >> 14, e = gidx & 16383;
  const float* p = part + (long)h * 128 * 16384 + e;
  float s = 0.f;
  for (int c = 0; c < 128; c++) s += p[(long)c * 16384];
  kvsT[gidx] = f2b(s);
}

// ---------------------------------------------------------------- fused attention combine -> pre
__global__ __launch_bounds__(256) void k_num(const u16* __restrict__ z0, const u16* __restrict__ gnn,
                                             const u16* __restrict__ kvsT,
                                             const u16* __restrict__ wts, const float* __restrict__ bqkv,
                                             const float* __restrict__ ksum, const float* __restrict__ SqSk,
                                             const float* __restrict__ g2, const float* __restrict__ b2,
                                             u16* __restrict__ pre) {
  __shared__ u16 sZ[64 * 136];
  __shared__ u16 sQ[64 * 136];
  int t = threadIdx.x;
  long n0 = (long)blockIdx.x * 64;
  int wave = t >> 6, lane = t & 63, m = lane & 15, g = lane >> 4;
#pragma unroll
  for (int i = 0; i < 4; i++) {
    int idx = t + i * 256; int row = idx >> 4, ch = idx & 15;
    *(float4*)(sZ + row * 136 + ch * 8) = *(const float4*)(z0 + (n0 + row) * 128 + ch * 8);
  }
  __syncthreads();
  float inv = rsqrtf(SqSk[0] * SqSk[1]);
  const u16* aB = sZ + (wave * 16 + m) * 136 + g * 8;
  short8 a[4];
#pragma unroll
  for (int s = 0; s < 4; s++) a[s] = *(const short8*)(aB + s * 32);
  f32x4 attn[8];
#pragma unroll
  for (int c = 0; c < 8; c++) attn[c] = (f32x4){0.f, 0.f, 0.f, 0.f};
  for (int h = 0; h < 4; h++) {
    const u16* wq = wts + 131072 + (long)h * 16384;
    const u16* wv = wts + 262144 + (long)h * 16384;
    f32x4 accq[8], accv[8];
#pragma unroll
    for (int c = 0; c < 8; c++) { accq[c] = (f32x4){0.f,0.f,0.f,0.f}; accv[c] = accq[c]; }
#pragma unroll
    for (int s = 0; s < 4; s++) {
#pragma unroll
      for (int c = 0; c < 8; c++) {
        long wo = (long)(c * 16 + m) * 128 + g * 8 + s * 32;
        short8 bqf = *(const short8*)(wq + wo);
        short8 bvf = *(const short8*)(wv + wo);
        accq[c] = __builtin_amdgcn_mfma_f32_16x16x32_bf16(a[s], bqf, accq[c], 0, 0, 0);
        accv[c] = __builtin_amdgcn_mfma_f32_16x16x32_bf16(a[s], bvf, accv[c], 0, 0, 0);
      }
    }
    float ks[8];
#pragma unroll
    for (int c = 0; c < 8; c++) {
      float qb_ = bqkv[h * 128 + c * 16 + m];
      float vb_ = bqkv[1024 + h * 128 + c * 16 + m];
      ks[c] = ksum[h * 128 + c * 16 + m];
#pragma unroll
      for (int r = 0; r < 4; r++) { accq[c][r] += qb_; accv[c][r] += vb_; }
    }
    float denr[4];
#pragma unroll
    for (int r = 0; r < 4; r++) {
      float s = 0.f;
#pragma unroll
      for (int c = 0; c < 8; c++) s += accq[c][r] * ks[c];
#pragma unroll
      for (int mask = 1; mask < 16; mask <<= 1) s += __shfl_xor(s, mask);
      denr[r] = s * inv + 65536.0f;
    }
    __syncthreads();   // previous head's sQ readers done
#pragma unroll
    for (int c = 0; c < 8; c++)
#pragma unroll
      for (int r = 0; r < 4; r++)
        sQ[(wave * 16 + g * 4 + r) * 136 + c * 16 + m] = f2b(accq[c][r]);
    __syncthreads();
    const u16* aQ = sQ + (wave * 16 + m) * 136 + g * 8;
    const u16* kb = kvsT + h * 16384;
    f32x4 accd[8];
#pragma unroll
    for (int c = 0; c < 8; c++) accd[c] = (f32x4){0.f, 0.f, 0.f, 0.f};
#pragma unroll
    for (int s = 0; s < 4; s++) {
      short8 aq = *(const short8*)(aQ + s * 32);
#pragma unroll
      for (int c = 0; c < 8; c++) {
        short8 bb = *(const short8*)(kb + (long)(c * 16 + m) * 128 + g * 8 + s * 32);
        accd[c] = __builtin_amdgcn_mfma_f32_16x16x32_bf16(aq, bb, accd[c], 0, 0, 0);
      }
    }
#pragma unroll
    for (int c = 0; c < 8; c++)
#pragma unroll
      for (int r = 0; r < 4; r++)
        attn[c][r] += (accd[c][r] * inv + 65536.0f * accv[c][r]) / denr[r];
  }
  // epilogue: y = 0.125*attn + 0.5*z0; LN; relu; blend with gnn
  float y[8][4];
#pragma unroll
  for (int c = 0; c < 8; c++)
#pragma unroll
    for (int r = 0; r < 4; r++)
      y[c][r] = 0.125f * attn[c][r] + 0.5f * b2f(sZ[(wave * 16 + g * 4 + r) * 136 + c * 16 + m]);
  float mu[4], rstd[4];
#pragma unroll
  for (int r = 0; r < 4; r++) {
    float s1 = 0.f, s2 = 0.f;
#pragma unroll
    for (int c = 0; c < 8; c++) { float v = y[c][r]; s1 += v; s2 += v * v; }
#pragma unroll
    for (int mask = 1; mask < 16; mask <<= 1) { s1 += __shfl_xor(s1, mask); s2 += __shfl_xor(s2, mask); }
    float mm2 = s1 * (1.f / 128.f);
    mu[r] = mm2; rstd[r] = rsqrtf(s2 * (1.f / 128.f) - mm2 * mm2 + 1e-5f);
  }
#pragma unroll
  for (int c = 0; c < 8; c++) {
    int d = c * 16 + m;
    float gg = g2[d], bb = b2[d];
#pragma unroll
    for (int r = 0; r < 4; r++) {
      long rowg = n0 + wave * 16 + g * 4 + r;
      float zr = fmaxf((y[c][r] - mu[r]) * rstd[r] * gg + bb, 0.f);
      pre[rowg * 128 + d] = f2b(0.8f * b2f(gnn[rowg * 128 + d]) + 0.2f * zr);
    }
  }
}

// ---------------------------------------------------------------- decoder (fp32 math)
__global__ __launch_bounds__(256) void k_decoder(const u16* __restrict__ enh, const int* __restrict__ cidx,
                                                 const u16* __restrict__ kd, const u16* __restrict__ vd,
                                                 const float* __restrict__ dWq, const float* __restrict__ dWo,
                                                 const float* __restrict__ ln1g, const float* __restrict__ ln1b,
                                                 const float* __restrict__ fW1, const float* __restrict__ fb1,
                                                 const float* __restrict__ fW2, const float* __restrict__ fb2,
                                                 const float* __restrict__ ln2g, const float* __restrict__ ln2b,
                                                 float* __restrict__ curO, float* __restrict__ globO) {
  __shared__ float cur[128], qd[128], att[128], tv[128], tn[128], f1[512];
  __shared__ float sc[4096];
  __shared__ float mu_s, rs_s;
  int b = blockIdx.x, t = threadIdx.x;
  int ci = cidx[b];
  const u16* eb = enh + (long)b * 1024 * 128;
  if (t < 128) cur[t] = b2f(eb[(long)ci * 128 + t]);
  __syncthreads();
  if (t < 128) {
    float s = 0.f;
    for (int k = 0; k < 128; k++) s += cur[k] * dWq[k * 128 + t];
    qd[t] = s;
  }
  __syncthreads();
  for (int i = 0; i < 16; i++) {
    int idx = t + 256 * i; int h = idx >> 10, n = idx & 1023;
    const u16* kr = kd + ((long)b * 1024 + n) * 128 + h * 32;
    float s = 0.f;
#pragma unroll
    for (int e = 0; e < 32; e++) s += qd[h * 32 + e] * b2f(kr[e]);
    sc[idx] = s * 0.17677669529663687f;
  }
  __syncthreads();
  {
    int h0 = t >> 6, j = t & 63;
    float mx = -1e30f;
    for (int k = 0; k < 16; k++) mx = fmaxf(mx, sc[h0 * 1024 + j + 64 * k]);
    for (int o = 32; o > 0; o >>= 1) mx = fmaxf(mx, __shfl_down(mx, o));
    mx = __shfl(mx, 0);
    float sm = 0.f;
    for (int k = 0; k < 16; k++) { float e2 = __expf(sc[h0 * 1024 + j + 64 * k] - mx); sc[h0 * 1024 + j + 64 * k] = e2; sm += e2; }
    for (int o = 32; o > 0; o >>= 1) sm += __shfl_down(sm, o);
    sm = __shfl(sm, 0);
    float invs = 1.0f / sm;
    for (int k = 0; k < 16; k++) sc[h0 * 1024 + j + 64 * k] *= invs;
  }
  __syncthreads();
  if (t < 128) {
    int h = t >> 5, e = t & 31;
    const u16* vb = vd + (long)b * 1024 * 128 + h * 32 + e;
    float s = 0.f;
    for (int n = 0; n < 1024; n++) s += sc[h * 1024 + n] * b2f(vb[(long)n * 128]);
    att[t] = s;
  }
  __syncthreads();
  if (t < 128) {
    float s = 0.f;
    for (int k = 0; k < 128; k++) s += att[k] * dWo[k * 128 + t];
    tv[t] = cur[t] + s;
  }
  __syncthreads();
  if (t == 0) {
    float s1 = 0.f, s2 = 0.f;
    for (int i = 0; i < 128; i++) { float v = tv[i]; s1 += v; s2 += v * v; }
    float mm = s1 / 128.0f;
    mu_s = mm; rs_s = rsqrtf(s2 / 128.0f - mm * mm + 1e-5f);
  }
  __syncthreads();
  if (t < 128) tn[t] = (tv[t] - mu_s) * rs_s * ln1g[t] + ln1b[t];
  __syncthreads();
  for (int i = 0; i < 2; i++) {
    int c = t + 256 * i;
    float s = fb1[c];
    for (int k = 0; k < 128; k++) s += tn[k] * fW1[k * 512 + c];
    f1[c] = fmaxf(s, 0.0f);
  }
  __syncthreads();
  if (t < 128) {
    float s = fb2[t];
    for (int k = 0; k < 512; k++) s += f1[k] * fW2[k * 128 + t];
    tv[t] = tn[t] + s;
  }
  __syncthreads();
  if (t == 0) {
    float s1 = 0.f, s2 = 0.f;
    for (int i = 0; i < 128; i++) { float v = tv[i]; s1 += v; s2 += v * v; }
    float mm = s1 / 128.0f;
    mu_s = mm; rs_s = rsqrtf(s2 / 128.0f - mm * mm + 1e-5f);
  }
  __syncthreads();
  if (t < 128) {
    globO[b * 128 + t] = (tv[t] - mu_s) * rs_s * ln2g[t] + ln2b[t];
    curO[b * 128 + t] = cur[t];
  }
}

// ---------------------------------------------------------------- Q head
__global__ __launch_bounds__(128) void k_qhead(const u16* __restrict__ enh, const int* __restrict__ vps,
                                               const float* __restrict__ curb, const float* __restrict__ globb,
                                               const float* __restrict__ qW, const float* __restrict__ qb,
                                               float* __restrict__ out) {
  __shared__ float red[128];
  __shared__ float base_s;
  int b = blockIdx.x, t = threadIdx.x;
  red[t] = globb[b * 128 + t] * qW[t] + curb[b * 128 + t] * qW[128 + t];
  __syncthreads();
  for (int o = 64; o > 0; o >>= 1) { if (t < o) red[t] += red[t + o]; __syncthreads(); }
  if (t == 0) base_s = red[0] + qb[0];
  __syncthreads();
  int vi = vps[b * 128 + t];
  const u16* er = enh + ((long)b * 1024 + vi) * 128;
  float s = 0.f;
  for (int i = 0; i < 128; i++) s += b2f(er[i]) * qW[256 + i];
  out[b * 128 + t] = base_s + s;
}

// ================================================================ launch
extern "C" void kernel_launch(void* const* d_in, const int* in_sizes, int n_in,
                              void* d_out, int out_size, void* d_ws, size_t ws_size,
                              hipStream_t stream) {
  const float* node_in = (const float*)d_in[0];
  const int* cur_idx   = (const int*)d_in[2];
  const int* vps       = (const int*)d_in[3];
  const int* adj       = (const int*)d_in[5];
  const float* W_init  = (const float*)d_in[6];
  const float* b_init  = (const float*)d_in[7];
  const float* gcn_W   = (const float*)d_in[8];
  const float* gcn_b   = (const float*)d_in[9];
  const float* tc_fc_W = (const float*)d_in[10];
  const float* tc_fc_b = (const float*)d_in[11];
  const float* ln1g    = (const float*)d_in[12];
  const float* ln1b    = (const float*)d_in[13];
  const float* Wq      = (const float*)d_in[14];
  const float* bq      = (const float*)d_in[15];
  const float* Wk      = (const float*)d_in[16];
  const float* bk      = (const float*)d_in[17];
  const float* Wv      = (const float*)d_in[18];
  const float* bv      = (const float*)d_in[19];
  const float* ln2g    = (const float*)d_in[20];
  const float* ln2b    = (const float*)d_in[21];
  const float* sg_W    = (const float*)d_in[22];
  const float* sg_b    = (const float*)d_in[23];
  const float* dWq     = (const float*)d_in[24];
  const float* dWk     = (const float*)d_in[25];
  const float* dWv     = (const float*)d_in[26];
  const float* dWo     = (const float*)d_in[27];
  const float* dln1g   = (const float*)d_in[28];
  const float* dln1b   = (const float*)d_in[29];
  const float* fW1     = (const float*)d_in[30];
  const float* fb1     = (const float*)d_in[31];
  const float* fW2     = (const float*)d_in[32];
  const float* fb2     = (const float*)d_in[33];
  const float* dln2g   = (const float*)d_in[34];
  const float* dln2b   = (const float*)d_in[35];
  const float* qW      = (const float*)d_in[36];
  const float* qb      = (const float*)d_in[37];

  char* base = (char*)d_ws;
  // [0,16.8M) bufA: x0 -> gcn ping -> gnn -> kd
  // [16.8M,33.6M) bufB: z0 -> vd
  // [33.6M,50.3M) bufC: gcn temp -> pre -> enh (in-place)
  // [50.3M,83.9M) part fp32 [4][128][16384]
  // [83.9M,~85M) small
  u16* bufA = (u16*)base;
  u16* bufB = (u16*)(base + 16777216);
  u16* bufC = (u16*)(base + 33554432);
  float* part = (float*)(base + 50331648);
  char* sm = base + 83886080;
  u16* kvsT   = (u16*)sm;                           // 65536 u16
  u16* wts    = (u16*)(sm + 131072);                // 327680 u16
  float* bqkv = (float*)(sm + 131072 + 655360);     // 1536
  float* ksum = bqkv + 1536;                        // 512
  float* SqSk = ksum + 512;                         // 2
  float* dinv = SqSk + 2;                           // 65536
  float* curb = dinv + BNn;                         // 8192
  float* globb= curb + 8192;                        // 8192

  k_prep<<<1280, 256, 0, stream>>>(gcn_W, tc_fc_W, sg_W, dWk, dWv, Wq, Wk, Wv, bq, bk, bv, wts, bqkv);
  k_embed<<<BNn / 2, 256, 0, stream>>>(node_in, W_init, b_init, bufA);
  k_deg<<<BNn / 256, 256, 0, stream>>>(adj, dinv);
  k_zero<<<3, 256, 0, stream>>>(ksum, 514);

  // z0 = relu(LN(x0 @ tc_fc + b)) -> bufB
  k_gemm<2><<<1024, 256, 0, stream>>>(bufA, wts + 4 * 16384, tc_fc_b, ln1g, ln1b, bufB);

  // GCN x4: gemm(bufA->bufC), agg(bufC->bufA)
  k_gemm<0><<<1024, 256, 0, stream>>>(bufA, wts + 0 * 16384, nullptr, nullptr, nullptr, bufC);
  k_agg<<<BNn / 2, 256, 0, stream>>>(bufC, adj, dinv, gcn_b + 0, bufA, 1);
  k_gemm<0><<<1024, 256, 0, stream>>>(bufA, wts + 1 * 16384, nullptr, nullptr, nullptr, bufC);
  k_agg<<<BNn / 2, 256, 0, stream>>>(bufC, adj, dinv, gcn_b + 128, bufA, 1);
  k_gemm<0><<<1024, 256, 0, stream>>>(bufA, wts + 2 * 16384, nullptr, nullptr, nullptr, bufC);
  k_agg<<<BNn / 2, 256, 0, stream>>>(bufC, adj, dinv, gcn_b + 256, bufA, 1);
  k_gemm<0><<<1024, 256, 0, stream>>>(bufA, wts + 3 * 16384, nullptr, nullptr, nullptr, bufC);
  k_agg<<<BNn / 2, 256, 0, stream>>>(bufC, adj, dinv, gcn_b + 384, bufA, 0);   // gnn -> bufA

  // fused qkv + kT*v partials + norms
  k_kvq<<<dim3(128, 4), 256, 0, stream>>>(bufB, wts, bqkv, part, ksum, SqSk, SqSk + 1);
  k_kvs_reduce<<<256, 256, 0, stream>>>(part, kvsT);

  // fused attention combine -> pre (bufC)
  k_num<<<1024, 256, 0, stream>>>(bufB, bufA, kvsT, wts, bqkv, ksum, SqSk, ln2g, ln2b, bufC);

  // enhanced = pre @ sg_fc + b (in-place bufC)
  k_gemm<0><<<1024, 256, 0, stream>>>(bufC, wts + 5 * 16384, sg_b, nullptr, nullptr, bufC);
  // decoder projections: kd -> bufA (gnn dead), vd -> bufB (z0 dead)
  k_gemm<0><<<1024, 256, 0, stream>>>(bufC, wts + 6 * 16384, nullptr, nullptr, nullptr, bufA);
  k_gemm<0><<<1024, 256, 0, stream>>>(bufC, wts + 7 * 16384, nullptr, nullptr, nullptr, bufB);

  k_decoder<<<64, 256, 0, stream>>>(bufC, cur_idx, bufA, bufB, dWq, dWo, dln1g, dln1b,
                                    fW1, fb1, fW2, fb2, dln2g, dln2b, curb, globb);
  k_qhead<<<64, 128, 0, stream>>>(bufC, vps, curb, globb, qW, qb, (float*)d_out);
}

// Round 5
// 720.586 us; speedup vs baseline: 3.3971x; 1.3661x over previous
//
#include <hip/hip_runtime.h>

#define BNn 65536L   // B*N

typedef unsigned short u16;
typedef unsigned int u32;
typedef __attribute__((ext_vector_type(8))) short short8;
typedef __attribute__((ext_vector_type(4))) float f32x4;

__device__ inline u16 f2b(float f){ u32 u = __float_as_uint(f); u32 r = (u + 0x7fffu + ((u>>16)&1u))>>16; return (u16)r; }
__device__ inline float b2f(u16 b){ return __uint_as_float(((u32)b)<<16); }

// ---------------------------------------------------------------- weight prep: fp32 [K][N] -> bf16 [N][K]
__global__ void k_prep(const float* __restrict__ gcnW, const float* __restrict__ tcW,
                       const float* __restrict__ sgW, const float* __restrict__ dKW,
                       const float* __restrict__ dVW,
                       const float* __restrict__ Wq, const float* __restrict__ Wk, const float* __restrict__ Wv,
                       const float* __restrict__ bq, const float* __restrict__ bk, const float* __restrict__ bv,
                       u16* __restrict__ wts, float* __restrict__ bqkv) {
  int idx = blockIdx.x * 256 + threadIdx.x;
  if (idx < 1536) bqkv[idx] = idx < 512 ? bq[idx] : idx < 1024 ? bk[idx - 512] : bv[idx - 1024];
  if (idx >= 327680) return;
  if (idx < 131072) {
    int mtx = idx >> 14;            // 0..3 gcn, 4 tc, 5 sg, 6 dk, 7 dv
    int loc = idx & 16383; int n = loc >> 7, k = loc & 127;
    const float* src = mtx < 4 ? gcnW + mtx * 16384 : mtx == 4 ? tcW : mtx == 5 ? sgW : mtx == 6 ? dKW : dVW;
    wts[idx] = f2b(src[k * 128 + n]);
  } else {
    int loc = idx - 131072; int n = loc >> 7, k = loc & 127;   // n in [0,1536)
    int sec = n >> 9, col = n & 511;
    const float* src = sec == 0 ? Wq : sec == 1 ? Wk : Wv;
    wts[idx] = f2b(src[k * 512 + col]);
  }
}

// ---------------------------------------------------------------- embed
__global__ __launch_bounds__(256) void k_embed(const float* __restrict__ in,
                                               const float* __restrict__ W,
                                               const float* __restrict__ b,
                                               u16* __restrict__ x0) {
  __shared__ float Ws[8 * 128];
  __shared__ float bs[128];
  __shared__ float ins[16];
  int t = threadIdx.x;
  for (int i = t; i < 1024; i += 256) Ws[i] = W[i];
  if (t < 128) bs[t] = b[t];
  int row0 = blockIdx.x * 2;
  if (t < 16) ins[t] = in[row0 * 8 + t];
  __syncthreads();
  int r = t >> 7, c = t & 127;
  float acc = bs[c];
#pragma unroll
  for (int k = 0; k < 8; k++) acc += ins[r * 8 + k] * Ws[k * 128 + c];
  x0[(long)(row0 + r) * 128 + c] = f2b(acc);
}

__global__ void k_deg(const int* __restrict__ adj, float* __restrict__ dinv) {
  int n = blockIdx.x * 256 + threadIdx.x;
  int cnt = 0;
#pragma unroll
  for (int j = 0; j < 16; j++) cnt += (adj[(long)n * 16 + j] >= 0) ? 1 : 0;
  dinv[n] = rsqrtf((float)cnt + 1.0f);
}

__global__ void k_zero(float* __restrict__ p, int n) {
  int i = blockIdx.x * 256 + threadIdx.x;
  if (i < n) p[i] = 0.0f;
}

// ---------------------------------------------------------------- MFMA GEMM 64-row tile: C = A[BN,128]@WT^T (+bias)
// EPI: 0 bias, 1 bias+relu, 2 bias+LN+relu. In-place safe. CT (optional) gets C transposed [128][BN].
template<int EPI>
__global__ __launch_bounds__(256) void k_gemm(const u16* __restrict__ A,
                                              const u16* __restrict__ WT,
                                              const float* __restrict__ bias,
                                              const float* __restrict__ lng,
                                              const float* __restrict__ lnb,
                                              u16* __restrict__ C,
                                              u16* __restrict__ CT) {
  __shared__ u16 sA[64 * 136];
  __shared__ u16 sW[128 * 136];
  int t = threadIdx.x;
  long row0 = (long)blockIdx.x * 64;
#pragma unroll
  for (int i = 0; i < 4; i++) {
    int idx = t + i * 256; int row = idx >> 4, ch = idx & 15;
    *(float4*)(sA + row * 136 + ch * 8) = *(const float4*)(A + (row0 + row) * 128 + ch * 8);
  }
#pragma unroll
  for (int i = 0; i < 8; i++) {
    int idx = t + i * 256; int row = idx >> 4, ch = idx & 15;
    *(float4*)(sW + row * 136 + ch * 8) = *(const float4*)(WT + row * 128 + ch * 8);
  }
  __syncthreads();
  int wave = t >> 6, lane = t & 63, m = lane & 15, g = lane >> 4;
  f32x4 acc[8];
#pragma unroll
  for (int c = 0; c < 8; c++) acc[c] = (f32x4){0.f, 0.f, 0.f, 0.f};
  const u16* aB = sA + (wave * 16 + m) * 136 + g * 8;
#pragma unroll
  for (int s = 0; s < 4; s++) {
    short8 a = *(const short8*)(aB + s * 32);
#pragma unroll
    for (int c = 0; c < 8; c++) {
      short8 bb = *(const short8*)(sW + (c * 16 + m) * 136 + g * 8 + s * 32);
      acc[c] = __builtin_amdgcn_mfma_f32_16x16x32_bf16(a, bb, acc[c], 0, 0, 0);
    }
  }
#pragma unroll
  for (int c = 0; c < 8; c++) {
    float bc = bias ? bias[c * 16 + m] : 0.0f;
#pragma unroll
    for (int r = 0; r < 4; r++) acc[c][r] += bc;
  }
  if (EPI == 2) {
    float gg[8], bb2[8];
#pragma unroll
    for (int c = 0; c < 8; c++) { gg[c] = lng[c * 16 + m]; bb2[c] = lnb[c * 16 + m]; }
#pragma unroll
    for (int r = 0; r < 4; r++) {
      float s1 = 0.f, s2 = 0.f;
#pragma unroll
      for (int c = 0; c < 8; c++) { float y = acc[c][r]; s1 += y; s2 += y * y; }
#pragma unroll
      for (int mask = 1; mask < 16; mask <<= 1) { s1 += __shfl_xor(s1, mask); s2 += __shfl_xor(s2, mask); }
      float mu = s1 * (1.f / 128.f);
      float rstd = rsqrtf(s2 * (1.f / 128.f) - mu * mu + 1e-5f);
#pragma unroll
      for (int c = 0; c < 8; c++)
        acc[c][r] = fmaxf((acc[c][r] - mu) * rstd * gg[c] + bb2[c], 0.f);
    }
  }
#pragma unroll
  for (int c = 0; c < 8; c++) {
    int col = c * 16 + m;
    u16 ob[4];
#pragma unroll
    for (int r = 0; r < 4; r++) {
      float y = acc[c][r];
      if (EPI == 1) y = fmaxf(y, 0.f);
      ob[r] = f2b(y);
      C[(row0 + wave * 16 + g * 4 + r) * 128 + col] = ob[r];
    }
    if (CT) {
      uint2 p;
      p.x = ((u32)ob[1] << 16) | ob[0]; p.y = ((u32)ob[3] << 16) | ob[2];
      *(uint2*)(CT + (long)col * BNn + row0 + wave * 16 + g * 4) = p;
    }
  }
}

// ---------------------------------------------------------------- GCN aggregate
__global__ __launch_bounds__(256) void k_agg(const u16* __restrict__ hw, const int* __restrict__ adj,
                                             const float* __restrict__ dinv, const float* __restrict__ gb,
                                             u16* __restrict__ out, int relu) {
  __shared__ float en[2][16];
  __shared__ int cols[2][16];
  int t = threadIdx.x;
  int row0 = blockIdx.x * 2;
  if (t < 32) {
    int lr = t >> 4, j = t & 15;
    int n = row0 + lr;
    int bb = n >> 10;
    int a = adj[(long)n * 16 + j];
    int valid = a >= 0;
    int cc = (valid ? a : 0) + (bb << 10);
    cols[lr][j] = cc;
    en[lr][j] = valid ? dinv[n] * dinv[cc] : 0.0f;
  }
  __syncthreads();
  int lr = t >> 7, c = t & 127;
  int n = row0 + lr;
  float di = dinv[n];
  float acc = b2f(hw[(long)n * 128 + c]) * di * di + gb[c];
#pragma unroll
  for (int j = 0; j < 16; j++) acc += en[lr][j] * b2f(hw[(long)cols[lr][j] * 128 + c]);
  out[(long)n * 128 + c] = f2b(relu ? fmaxf(acc, 0.0f) : acc);
}

// ---------------------------------------------------------------- Gram: Gpart[blk] = Zslice^T Zslice, + zsum
__global__ __launch_bounds__(256) void k_gram(const u16* __restrict__ z0T,
                                              float* __restrict__ Gpart, float* __restrict__ zsum) {
  __shared__ u16 sZT[128 * 264];
  int t = threadIdx.x;
  long k0 = (long)blockIdx.x * 256;
#pragma unroll
  for (int i = 0; i < 16; i++) {
    int idx = t + i * 256; int m = idx >> 5, ch = idx & 31;
    *(float4*)(sZT + m * 264 + ch * 8) = *(const float4*)(z0T + (long)m * BNn + k0 + ch * 8);
  }
  __syncthreads();
  int wave = t >> 6, lane = t & 63, m = lane & 15, g = lane >> 4;
  f32x4 acc[2][8];
#pragma unroll
  for (int i = 0; i < 2; i++)
#pragma unroll
    for (int c = 0; c < 8; c++) acc[i][c] = (f32x4){0.f, 0.f, 0.f, 0.f};
#pragma unroll
  for (int kk = 0; kk < 8; kk++) {
    short8 a0 = *(const short8*)(sZT + (wave * 32 + m) * 264 + kk * 32 + g * 8);
    short8 a1 = *(const short8*)(sZT + (wave * 32 + 16 + m) * 264 + kk * 32 + g * 8);
#pragma unroll
    for (int c = 0; c < 8; c++) {
      short8 bb = *(const short8*)(sZT + (c * 16 + m) * 264 + kk * 32 + g * 8);
      acc[0][c] = __builtin_amdgcn_mfma_f32_16x16x32_bf16(a0, bb, acc[0][c], 0, 0, 0);
      acc[1][c] = __builtin_amdgcn_mfma_f32_16x16x32_bf16(a1, bb, acc[1][c], 0, 0, 0);
    }
  }
  if (t < 128) {
    float s = 0.f;
    for (int j = 0; j < 256; j++) s += b2f(sZT[t * 264 + j]);
    atomicAdd(&zsum[t], s);
  }
  // lane-linear coalesced partial write (permuted layout; reduce kernel inverts it)
  float* P = Gpart + (long)blockIdx.x * 16384 + wave * 4096;
#pragma unroll
  for (int i = 0; i < 2; i++)
#pragma unroll
    for (int c = 0; c < 8; c++)
      *(f32x4*)(P + (i * 8 + c) * 256 + lane * 4) = acc[i][c];
}

// ---------------------------------------------------------------- reduce Gram partials -> G fp32 [128][128]
__global__ void k_gram_red(const float* __restrict__ Gpart, float* __restrict__ G) {
  int tid = blockIdx.x * 256 + threadIdx.x;   // 0..4095
  int wave = tid >> 10, ic = (tid >> 6) & 15, lane = tid & 63;
  int i = ic >> 3, c = ic & 7, m = lane & 15, g = lane >> 4;
  const float* p = Gpart + (long)tid * 4;
  float s0 = 0.f, s1 = 0.f, s2 = 0.f, s3 = 0.f;
  for (int b = 0; b < 256; b++) {
    f32x4 v = *(const f32x4*)(p + (long)b * 16384);
    s0 += v[0]; s1 += v[1]; s2 += v[2]; s3 += v[3];
  }
  int mj = c * 16 + m;
  int mi = wave * 32 + i * 16 + g * 4;
  G[(mi + 0) * 128 + mj] = s0;
  G[(mi + 1) * 128 + mj] = s1;
  G[(mi + 2) * 128 + mj] = s2;
  G[(mi + 3) * 128 + mj] = s3;
}

// ---------------------------------------------------------------- ksum[col] = Wk(:,col).zsum + BN*bk[col]
__global__ void k_ksum(const float* __restrict__ Wk, const float* __restrict__ bk,
                       const float* __restrict__ zsum, float* __restrict__ ksum) {
  int c = blockIdx.x * 256 + threadIdx.x;   // 512
  float s = 0.f;
  for (int i = 0; i < 128; i++) s += Wk[i * 512 + c] * zsum[i];
  ksum[c] = s + 65536.0f * bk[c];
}

// ---------------------------------------------------------------- Sq/Sk: sum_col [w^T G w + 2 b (w.zsum) + BN b^2]
__global__ __launch_bounds__(256) void k_sqsk(const float* __restrict__ Wq, const float* __restrict__ bq,
                                              const float* __restrict__ Wk, const float* __restrict__ bk,
                                              const float* __restrict__ G, const float* __restrict__ zsum,
                                              float* __restrict__ Sq, float* __restrict__ Sk) {
  __shared__ float wcol[128];
  __shared__ float red[256];
  int t = threadIdx.x;
  int isK = blockIdx.x >> 6;
  const float* W = isK ? Wk : Wq;
  const float* bb = isK ? bk : bq;
  float* S = isK ? Sk : Sq;
  int c0 = (blockIdx.x & 63) * 8;
  float tot = 0.f;
  for (int cc = 0; cc < 8; cc++) {
    int c = c0 + cc;
    __syncthreads();
    if (t < 128) wcol[t] = W[t * 512 + c];
    __syncthreads();
    float v = 0.f;
    if (t < 128) {
      float uu = 0.f;
      for (int j = 0; j < 128; j++) uu += G[t * 128 + j] * wcol[j];
      v = uu * wcol[t] + 2.0f * bb[c] * wcol[t] * zsum[t];
    }
    red[t] = v;
    __syncthreads();
    for (int o = 128; o > 0; o >>= 1) { if (t < o) red[t] += red[t + o]; __syncthreads(); }
    if (t == 0) tot += red[0] + 65536.0f * bb[c] * bb[c];
  }
  if (t == 0) atomicAdd(S, tot);
}

// ---------------------------------------------------------------- kvsT[h][d][m] = wk_m^T G wv_d + corrections
__global__ __launch_bounds__(256) void k_kvsT(const float* __restrict__ Wk, const float* __restrict__ Wv,
                                              const float* __restrict__ bk, const float* __restrict__ bv,
                                              const float* __restrict__ G, const float* __restrict__ zsum,
                                              const float* __restrict__ ksum, u16* __restrict__ kvsT) {
  __shared__ float wv8[128][8];
  __shared__ float U[128][8];
  __shared__ float zv[8];
  int t = threadIdx.x;
  int h = blockIdx.x >> 4, dg = blockIdx.x & 15;
  if (t < 128) {
#pragma unroll
    for (int dd = 0; dd < 8; dd++) wv8[t][dd] = Wv[t * 512 + h * 128 + dg * 8 + dd];
  }
  __syncthreads();
  {
    int i = t & 127, du = t >> 7;
    float a0 = 0.f, a1 = 0.f, a2 = 0.f, a3 = 0.f;
    for (int j = 0; j < 128; j++) {
      float gg = G[i * 128 + j];
      a0 += gg * wv8[j][du * 4 + 0]; a1 += gg * wv8[j][du * 4 + 1];
      a2 += gg * wv8[j][du * 4 + 2]; a3 += gg * wv8[j][du * 4 + 3];
    }
    U[i][du * 4 + 0] = a0; U[i][du * 4 + 1] = a1; U[i][du * 4 + 2] = a2; U[i][du * 4 + 3] = a3;
  }
  if (t < 8) {
    float s = 0.f;
    for (int i = 0; i < 128; i++) s += zsum[i] * wv8[i][t];
    zv[t] = s;
  }
  __syncthreads();
  {
    int m = t & 127, du = t >> 7;
    int colk = h * 128 + m;
    float bkm = bk[colk];
    float wkzs = ksum[colk] - 65536.0f * bkm;
    float a[4] = {0.f, 0.f, 0.f, 0.f};
    for (int i = 0; i < 128; i++) {
      float wk = Wk[i * 512 + colk];
#pragma unroll
      for (int q = 0; q < 4; q++) a[q] += wk * U[i][du * 4 + q];
    }
#pragma unroll
    for (int q = 0; q < 4; q++) {
      int dd = du * 4 + q;
      int cold = h * 128 + dg * 8 + dd;
      float val = a[q] + wkzs * bv[cold] + bkm * zv[dd] + 65536.0f * bkm * bv[cold];
      kvsT[h * 16384 + (dg * 8 + dd) * 128 + m] = f2b(val);
    }
  }
}

// ---------------------------------------------------------------- fused attention combine -> pre
__global__ __launch_bounds__(256) void k_num(const u16* __restrict__ z0, const u16* __restrict__ gnn,
                                             const u16* __restrict__ kvsT,
                                             const u16* __restrict__ wts, const float* __restrict__ bqkv,
                                             const float* __restrict__ ksum, const float* __restrict__ SqSk,
                                             const float* __restrict__ g2, const float* __restrict__ b2,
                                             u16* __restrict__ pre) {
  __shared__ u16 sZ[64 * 136];
  __shared__ u16 sQ[64 * 136];
  int t = threadIdx.x;
  long n0 = (long)blockIdx.x * 64;
  int wave = t >> 6, lane = t & 63, m = lane & 15, g = lane >> 4;
#pragma unroll
  for (int i = 0; i < 4; i++) {
    int idx = t + i * 256; int row = idx >> 4, ch = idx & 15;
    *(float4*)(sZ + row * 136 + ch * 8) = *(const float4*)(z0 + (n0 + row) * 128 + ch * 8);
  }
  __syncthreads();
  float inv = rsqrtf(SqSk[0] * SqSk[1]);
  const u16* aB = sZ + (wave * 16 + m) * 136 + g * 8;
  short8 a[4];
#pragma unroll
  for (int s = 0; s < 4; s++) a[s] = *(const short8*)(aB + s * 32);
  f32x4 attn[8];
#pragma unroll
  for (int c = 0; c < 8; c++) attn[c] = (f32x4){0.f, 0.f, 0.f, 0.f};
  for (int h = 0; h < 4; h++) {
    const u16* wq = wts + 131072 + (long)h * 16384;
    const u16* wv = wts + 262144 + (long)h * 16384;
    f32x4 accq[8], accv[8];
#pragma unroll
    for (int c = 0; c < 8; c++) { accq[c] = (f32x4){0.f,0.f,0.f,0.f}; accv[c] = accq[c]; }
#pragma unroll
    for (int s = 0; s < 4; s++) {
#pragma unroll
      for (int c = 0; c < 8; c++) {
        long wo = (long)(c * 16 + m) * 128 + g * 8 + s * 32;
        short8 bqf = *(const short8*)(wq + wo);
        short8 bvf = *(const short8*)(wv + wo);
        accq[c] = __builtin_amdgcn_mfma_f32_16x16x32_bf16(a[s], bqf, accq[c], 0, 0, 0);
        accv[c] = __builtin_amdgcn_mfma_f32_16x16x32_bf16(a[s], bvf, accv[c], 0, 0, 0);
      }
    }
    float ks[8];
#pragma unroll
    for (int c = 0; c < 8; c++) {
      float qb_ = bqkv[h * 128 + c * 16 + m];
      float vb_ = bqkv[1024 + h * 128 + c * 16 + m];
      ks[c] = ksum[h * 128 + c * 16 + m];
#pragma unroll
      for (int r = 0; r < 4; r++) { accq[c][r] += qb_; accv[c][r] += vb_; }
    }
    float denr[4];
#pragma unroll
    for (int r = 0; r < 4; r++) {
      float s = 0.f;
#pragma unroll
      for (int c = 0; c < 8; c++) s += accq[c][r] * ks[c];
#pragma unroll
      for (int mask = 1; mask < 16; mask <<= 1) s += __shfl_xor(s, mask);
      denr[r] = s * inv + 65536.0f;
    }
    __syncthreads();
#pragma unroll
    for (int c = 0; c < 8; c++)
#pragma unroll
      for (int r = 0; r < 4; r++)
        sQ[(wave * 16 + g * 4 + r) * 136 + c * 16 + m] = f2b(accq[c][r]);
    __syncthreads();
    const u16* aQ = sQ + (wave * 16 + m) * 136 + g * 8;
    const u16* kb = kvsT + h * 16384;
    f32x4 accd[8];
#pragma unroll
    for (int c = 0; c < 8; c++) accd[c] = (f32x4){0.f, 0.f, 0.f, 0.f};
#pragma unroll
    for (int s = 0; s < 4; s++) {
      short8 aq = *(const short8*)(aQ + s * 32);
#pragma unroll
      for (int c = 0; c < 8; c++) {
        short8 bb = *(const short8*)(kb + (long)(c * 16 + m) * 128 + g * 8 + s * 32);
        accd[c] = __builtin_amdgcn_mfma_f32_16x16x32_bf16(aq, bb, accd[c], 0, 0, 0);
      }
    }
#pragma unroll
    for (int c = 0; c < 8; c++)
#pragma unroll
      for (int r = 0; r < 4; r++)
        attn[c][r] += (accd[c][r] * inv + 65536.0f * accv[c][r]) / denr[r];
  }
  float y[8][4];
#pragma unroll
  for (int c = 0; c < 8; c++)
#pragma unroll
    for (int r = 0; r < 4; r++)
      y[c][r] = 0.125f * attn[c][r] + 0.5f * b2f(sZ[(wave * 16 + g * 4 + r) * 136 + c * 16 + m]);
  float mu[4], rstd[4];
#pragma unroll
  for (int r = 0; r < 4; r++) {
    float s1 = 0.f, s2 = 0.f;
#pragma unroll
    for (int c = 0; c < 8; c++) { float v = y[c][r]; s1 += v; s2 += v * v; }
#pragma unroll
    for (int mask = 1; mask < 16; mask <<= 1) { s1 += __shfl_xor(s1, mask); s2 += __shfl_xor(s2, mask); }
    float mm2 = s1 * (1.f / 128.f);
    mu[r] = mm2; rstd[r] = rsqrtf(s2 * (1.f / 128.f) - mm2 * mm2 + 1e-5f);
  }
#pragma unroll
  for (int c = 0; c < 8; c++) {
    int d = c * 16 + m;
    float gg = g2[d], bb = b2[d];
#pragma unroll
    for (int r = 0; r < 4; r++) {
      long rowg = n0 + wave * 16 + g * 4 + r;
      float zr = fmaxf((y[c][r] - mu[r]) * rstd[r] * gg + bb, 0.f);
      pre[rowg * 128 + d] = f2b(0.8f * b2f(gnn[rowg * 128 + d]) + 0.2f * zr);
    }
  }
}

// ---------------------------------------------------------------- decoder part 1: per (b,h) attention
__global__ __launch_bounds__(256) void k_dec1(const u16* __restrict__ enh, const int* __restrict__ cidx,
                                              const u16* __restrict__ kd, const u16* __restrict__ vd,
                                              const float* __restrict__ dWq, float* __restrict__ attg) {
  __shared__ float cur[128], qd[32], sc[1024], sred[4], rAtt[8][32];
  __shared__ float bcast;
  int b = blockIdx.x, h = blockIdx.y, t = threadIdx.x;
  int wave = t >> 6, lane = t & 63;
  int ci = cidx[b];
  if (t < 128) cur[t] = b2f(enh[((long)b * 1024 + ci) * 128 + t]);
  __syncthreads();
  if (t < 32) {
    float s = 0.f;
    for (int k = 0; k < 128; k++) s += cur[k] * dWq[k * 128 + h * 32 + t];
    qd[t] = s;
  }
  __syncthreads();
  float sc4[4];
  float mx = -1e30f;
#pragma unroll
  for (int q = 0; q < 4; q++) {
    int n = t * 4 + q;
    const u16* kr = kd + ((long)b * 1024 + n) * 128 + h * 32;
    float s = 0.f;
#pragma unroll
    for (int e8 = 0; e8 < 4; e8++) {
      short8 kv = *(const short8*)(kr + e8 * 8);
#pragma unroll
      for (int j = 0; j < 8; j++) s += qd[e8 * 8 + j] * b2f((u16)kv[j]);
    }
    sc4[q] = s * 0.17677669529663687f;
    mx = fmaxf(mx, sc4[q]);
  }
#pragma unroll
  for (int o = 1; o < 64; o <<= 1) mx = fmaxf(mx, __shfl_xor(mx, o));
  if (lane == 0) sred[wave] = mx;
  __syncthreads();
  float bm = fmaxf(fmaxf(sred[0], sred[1]), fmaxf(sred[2], sred[3]));
  float ls = 0.f;
#pragma unroll
  for (int q = 0; q < 4; q++) {
    float e = __expf(sc4[q] - bm);
    sc[t * 4 + q] = e;
    ls += e;
  }
#pragma unroll
  for (int o = 1; o < 64; o <<= 1) ls += __shfl_xor(ls, o);
  __syncthreads();   // sred reuse
  if (lane == 0) sred[wave] = ls;
  __syncthreads();
  if (t == 0) bcast = 1.0f / (sred[0] + sred[1] + sred[2] + sred[3]);
  __syncthreads();
  float invs = bcast;
  int e = t & 31, grp = t >> 5;
  float s = 0.f;
  for (int j = 0; j < 128; j++) {
    int n = grp * 128 + j;
    s += sc[n] * b2f(vd[((long)b * 1024 + n) * 128 + h * 32 + e]);
  }
  rAtt[grp][e] = s;
  __syncthreads();
  if (t < 32) {
    float a = 0.f;
#pragma unroll
    for (int gq = 0; gq < 8; gq++) a += rAtt[gq][t];
    attg[b * 128 + h * 32 + t] = a * invs;
  }
}

// ---------------------------------------------------------------- decoder part 2: Wo + LN + FF + LN
__global__ __launch_bounds__(256) void k_dec2(const u16* __restrict__ enh, const int* __restrict__ cidx,
                                              const float* __restrict__ attg, const float* __restrict__ dWo,
                                              const float* __restrict__ ln1g, const float* __restrict__ ln1b,
                                              const float* __restrict__ fW1, const float* __restrict__ fb1,
                                              const float* __restrict__ fW2, const float* __restrict__ fb2,
                                              const float* __restrict__ ln2g, const float* __restrict__ ln2b,
                                              float* __restrict__ curO, float* __restrict__ globO) {
  __shared__ float cur[128], tv[128], tn[128], f1[512], red[256];
  __shared__ float mu_s, rs_s;
  int b = blockIdx.x, t = threadIdx.x;
  int ci = cidx[b];
  if (t < 128) cur[t] = b2f(enh[((long)b * 1024 + ci) * 128 + t]);
  __syncthreads();
  if (t < 128) {
    float s = 0.f;
    for (int k = 0; k < 128; k++) s += attg[b * 128 + k] * dWo[k * 128 + t];
    tv[t] = cur[t] + s;
  }
  // LN1
  {
    float v = (t < 128) ? tv[t] : 0.f;
    red[t] = v; __syncthreads();
    for (int o = 128; o > 0; o >>= 1) { if (t < o) red[t] += red[t + o]; __syncthreads(); }
    float s1 = red[0];
    __syncthreads();
    red[t] = v * v; __syncthreads();
    for (int o = 128; o > 0; o >>= 1) { if (t < o) red[t] += red[t + o]; __syncthreads(); }
    if (t == 0) {
      float mm = s1 / 128.0f;
      mu_s = mm; rs_s = rsqrtf(red[0] / 128.0f - mm * mm + 1e-5f);
    }
    __syncthreads();
    if (t < 128) tn[t] = (tv[t] - mu_s) * rs_s * ln1g[t] + ln1b[t];
    __syncthreads();
  }
#pragma unroll
  for (int i = 0; i < 2; i++) {
    int c = t + 256 * i;
    float s = fb1[c];
    for (int k = 0; k < 128; k++) s += tn[k] * fW1[k * 512 + c];
    f1[c] = fmaxf(s, 0.0f);
  }
  __syncthreads();
  if (t < 128) {
    float s = fb2[t];
    for (int k = 0; k < 512; k++) s += f1[k] * fW2[k * 128 + t];
    tv[t] = tn[t] + s;
  }
  // LN2
  {
    __syncthreads();
    float v = (t < 128) ? tv[t] : 0.f;
    red[t] = v; __syncthreads();
    for (int o = 128; o > 0; o >>= 1) { if (t < o) red[t] += red[t + o]; __syncthreads(); }
    float s1 = red[0];
    __syncthreads();
    red[t] = v * v; __syncthreads();
    for (int o = 128; o > 0; o >>= 1) { if (t < o) red[t] += red[t + o]; __syncthreads(); }
    if (t == 0) {
      float mm = s1 / 128.0f;
      mu_s = mm; rs_s = rsqrtf(red[0] / 128.0f - mm * mm + 1e-5f);
    }
    __syncthreads();
  }
  if (t < 128) {
    globO[b * 128 + t] = (tv[t] - mu_s) * rs_s * ln2g[t] + ln2b[t];
    curO[b * 128 + t] = cur[t];
  }
}

// ---------------------------------------------------------------- Q head
__global__ __launch_bounds__(128) void k_qhead(const u16* __restrict__ enh, const int* __restrict__ vps,
                                               const float* __restrict__ curb, const float* __restrict__ globb,
                                               const float* __restrict__ qW, const float* __restrict__ qb,
                                               float* __restrict__ out) {
  __shared__ float red[128];
  __shared__ float base_s;
  int b = blockIdx.x, t = threadIdx.x;
  red[t] = globb[b * 128 + t] * qW[t] + curb[b * 128 + t] * qW[128 + t];
  __syncthreads();
  for (int o = 64; o > 0; o >>= 1) { if (t < o) red[t] += red[t + o]; __syncthreads(); }
  if (t == 0) base_s = red[0] + qb[0];
  __syncthreads();
  int vi = vps[b * 128 + t];
  const u16* er = enh + ((long)b * 1024 + vi) * 128;
  float s = 0.f;
  for (int i = 0; i < 128; i++) s += b2f(er[i]) * qW[256 + i];
  out[b * 128 + t] = base_s + s;
}

// ================================================================ launch
extern "C" void kernel_launch(void* const* d_in, const int* in_sizes, int n_in,
                              void* d_out, int out_size, void* d_ws, size_t ws_size,
                              hipStream_t stream) {
  const float* node_in = (const float*)d_in[0];
  const int* cur_idx   = (const int*)d_in[2];
  const int* vps       = (const int*)d_in[3];
  const int* adj       = (const int*)d_in[5];
  const float* W_init  = (const float*)d_in[6];
  const float* b_init  = (const float*)d_in[7];
  const float* gcn_W   = (const float*)d_in[8];
  const float* gcn_b   = (const float*)d_in[9];
  const float* tc_fc_W = (const float*)d_in[10];
  const float* tc_fc_b = (const float*)d_in[11];
  const float* ln1g    = (const float*)d_in[12];
  const float* ln1b    = (const float*)d_in[13];
  const float* Wq      = (const float*)d_in[14];
  const float* bq      = (const float*)d_in[15];
  const float* Wk      = (const float*)d_in[16];
  const float* bk      = (const float*)d_in[17];
  const float* Wv      = (const float*)d_in[18];
  const float* bv      = (const float*)d_in[19];
  const float* ln2g    = (const float*)d_in[20];
  const float* ln2b    = (const float*)d_in[21];
  const float* sg_W    = (const float*)d_in[22];
  const float* sg_b    = (const float*)d_in[23];
  const float* dWq     = (const float*)d_in[24];
  const float* dWk     = (const float*)d_in[25];
  const float* dWv     = (const float*)d_in[26];
  const float* dWo     = (const float*)d_in[27];
  const float* dln1g   = (const float*)d_in[28];
  const float* dln1b   = (const float*)d_in[29];
  const float* fW1     = (const float*)d_in[30];
  const float* fb1     = (const float*)d_in[31];
  const float* fW2     = (const float*)d_in[32];
  const float* fb2     = (const float*)d_in[33];
  const float* dln2g   = (const float*)d_in[34];
  const float* dln2b   = (const float*)d_in[35];
  const float* qW      = (const float*)d_in[36];
  const float* qb      = (const float*)d_in[37];

  char* base = (char*)d_ws;
  // [0,16.8M) bufA: x0 -> gcn ping -> gnn -> kd
  // [16.8,33.6M) bufB: z0 -> vd
  // [33.6,50.3M) bufC: gcn temp -> pre -> enh
  // [50.3,67.1M) z0T [128][BN]
  // [67.1,83.9M) Gpart [256][16384] fp32
  // [83.9M..) small
  u16* bufA = (u16*)base;
  u16* bufB = (u16*)(base + 16777216);
  u16* bufC = (u16*)(base + 33554432);
  u16* z0T  = (u16*)(base + 50331648);
  float* Gpart = (float*)(base + 67108864);
  char* sm = base + 83886080;
  u16* kvsT   = (u16*)sm;                           // 65536 u16
  u16* wts    = (u16*)(sm + 131072);                // 327680 u16
  float* bqkv = (float*)(sm + 131072 + 655360);     // 1536
  float* ksum = bqkv + 1536;                        // 512
  float* SqSk = ksum + 512;                         // 2
  float* zsum = SqSk + 2;                           // 128
  float* Gm   = zsum + 128;                         // 16384
  float* dinv = Gm + 16384;                         // 65536
  float* curb = dinv + BNn;                         // 8192
  float* globb= curb + 8192;                        // 8192
  float* attg = globb + 8192;                       // 8192

  k_prep<<<1280, 256, 0, stream>>>(gcn_W, tc_fc_W, sg_W, dWk, dWv, Wq, Wk, Wv, bq, bk, bv, wts, bqkv);
  k_embed<<<BNn / 2, 256, 0, stream>>>(node_in, W_init, b_init, bufA);
  k_deg<<<BNn / 256, 256, 0, stream>>>(adj, dinv);
  k_zero<<<1, 256, 0, stream>>>(SqSk, 130);   // Sq, Sk, zsum

  // z0 = relu(LN(x0 @ tc_fc + b)) -> bufB (+ z0T)
  k_gemm<2><<<1024, 256, 0, stream>>>(bufA, wts + 4 * 16384, tc_fc_b, ln1g, ln1b, bufB, z0T);

  // Gram chain: G = Z^T Z, zsum; then ksum/Sq/Sk/kvsT analytically
  k_gram<<<256, 256, 0, stream>>>(z0T, Gpart, zsum);
  k_gram_red<<<16, 256, 0, stream>>>(Gpart, Gm);
  k_ksum<<<2, 256, 0, stream>>>(Wk, bk, zsum, ksum);
  k_sqsk<<<128, 256, 0, stream>>>(Wq, bq, Wk, bk, Gm, zsum, SqSk, SqSk + 1);
  k_kvsT<<<64, 256, 0, stream>>>(Wk, Wv, bk, bv, Gm, zsum, ksum, kvsT);

  // GCN x4: gemm(bufA->bufC), agg(bufC->bufA)
  k_gemm<0><<<1024, 256, 0, stream>>>(bufA, wts + 0 * 16384, nullptr, nullptr, nullptr, bufC, nullptr);
  k_agg<<<BNn / 2, 256, 0, stream>>>(bufC, adj, dinv, gcn_b + 0, bufA, 1);
  k_gemm<0><<<1024, 256, 0, stream>>>(bufA, wts + 1 * 16384, nullptr, nullptr, nullptr, bufC, nullptr);
  k_agg<<<BNn / 2, 256, 0, stream>>>(bufC, adj, dinv, gcn_b + 128, bufA, 1);
  k_gemm<0><<<1024, 256, 0, stream>>>(bufA, wts + 2 * 16384, nullptr, nullptr, nullptr, bufC, nullptr);
  k_agg<<<BNn / 2, 256, 0, stream>>>(bufC, adj, dinv, gcn_b + 256, bufA, 1);
  k_gemm<0><<<1024, 256, 0, stream>>>(bufA, wts + 3 * 16384, nullptr, nullptr, nullptr, bufC, nullptr);
  k_agg<<<BNn / 2, 256, 0, stream>>>(bufC, adj, dinv, gcn_b + 384, bufA, 0);   // gnn -> bufA

  // fused attention combine -> pre (bufC)
  k_num<<<1024, 256, 0, stream>>>(bufB, bufA, kvsT, wts, bqkv, ksum, SqSk, ln2g, ln2b, bufC);

  // enhanced = pre @ sg_fc + b (in-place bufC)
  k_gemm<0><<<1024, 256, 0, stream>>>(bufC, wts + 5 * 16384, sg_b, nullptr, nullptr, bufC, nullptr);
  // decoder projections: kd -> bufA (gnn dead), vd -> bufB (z0 dead)
  k_gemm<0><<<1024, 256, 0, stream>>>(bufC, wts + 6 * 16384, nullptr, nullptr, nullptr, bufA, nullptr);
  k_gemm<0><<<1024, 256, 0, stream>>>(bufC, wts + 7 * 16384, nullptr, nullptr, nullptr, bufB, nullptr);

  k_dec1<<<dim3(64, 4), 256, 0, stream>>>(bufC, cur_idx, bufA, bufB, dWq, attg);
  k_dec2<<<64, 256, 0, stream>>>(bufC, cur_idx, attg, dWo, dln1g, dln1b,
                                 fW1, fb1, fW2, fb2, dln2g, dln2b, curb, globb);
  k_qhead<<<64, 128, 0, stream>>>(bufC, vps, curb, globb, qW, qb, (float*)d_out);
}